// Round 19
// baseline (618.197 us; speedup 1.0000x reference)
//
#include <hip/hip_runtime.h>

#define N_NODES 50000
#define N_EDGES 800000
#define IN_CH   128
#define OUT_CH  32
#define HEADS   10
#define HC      320           // HEADS*OUT_CH
#define N_GRAPHS 512
#define NEG_SLOPE 0.2f
#define NBLK_SCAN 196         // ceil(50000/256)

typedef __attribute__((ext_vector_type(8))) short bf16x8;   // 8 bf16 in 4 VGPRs
typedef __attribute__((ext_vector_type(4))) float f32x4;
typedef __attribute__((ext_vector_type(4))) unsigned short usx4;  // native 8B vec

__device__ __forceinline__ unsigned fmap(float f) {
  unsigned u = __float_as_uint(f);
  return (u & 0x80000000u) ? ~u : (u | 0x80000000u);
}
__device__ __forceinline__ float funmap(unsigned u) {
  u = (u & 0x80000000u) ? (u ^ 0x80000000u) : ~u;
  return __uint_as_float(u);
}
__device__ __forceinline__ float leaky(float a) {
  return a > 0.f ? a : NEG_SLOPE * a;
}
__device__ __forceinline__ unsigned short f2bf(float f) {
  unsigned u = __float_as_uint(f);
  return (unsigned short)((u + 0x7FFFu + ((u >> 16) & 1u)) >> 16);
}
__device__ __forceinline__ float bf2f(unsigned short b) {
  return __uint_as_float(((unsigned)b) << 16);
}
__device__ __forceinline__ float bflo(unsigned u) { return __uint_as_float(u << 16); }
__device__ __forceinline__ float bfhi(unsigned u) { return __uint_as_float(u & 0xFFFF0000u); }
__device__ __forceinline__ float elu(float v) {
  return v > 0.f ? v : expm1f(v);
}

// ============================ CSR construction =============================
__global__ __launch_bounds__(256) void hist_k(const int* __restrict__ ei,
                                              int* __restrict__ deg) {
  int e = blockIdx.x * 256 + threadIdx.x;
  if (e < N_EDGES) atomicAdd(&deg[ei[N_EDGES + e]], 1);
}

__global__ __launch_bounds__(256) void scan_blk(const int* __restrict__ deg,
                                                int* __restrict__ roff,
                                                int* __restrict__ bsum) {
  __shared__ int s[256];
  int i = blockIdx.x * 256 + threadIdx.x;
  int v = (i < N_NODES) ? deg[i] : 0;
  s[threadIdx.x] = v;
  __syncthreads();
  #pragma unroll
  for (int o = 1; o < 256; o <<= 1) {
    int t = (threadIdx.x >= o) ? s[threadIdx.x - o] : 0;
    __syncthreads();
    s[threadIdx.x] += t;
    __syncthreads();
  }
  if (i < N_NODES) roff[i] = s[threadIdx.x] - v;   // exclusive
  if (threadIdx.x == 255) bsum[blockIdx.x] = s[255];
}

__global__ __launch_bounds__(256) void scan_top(int* __restrict__ bsum) {
  __shared__ int s[256];
  int i = threadIdx.x;
  int v = (i < NBLK_SCAN) ? bsum[i] : 0;
  s[i] = v;
  __syncthreads();
  #pragma unroll
  for (int o = 1; o < 256; o <<= 1) {
    int t = (i >= o) ? s[i - o] : 0;
    __syncthreads();
    s[i] += t;
    __syncthreads();
  }
  if (i < NBLK_SCAN) bsum[i] = s[i] - v;           // exclusive
}

__global__ __launch_bounds__(256) void scan_add(int* __restrict__ roff,
                                                const int* __restrict__ bsum) {
  int i = blockIdx.x * 256 + threadIdx.x;
  if (i < N_NODES) roff[i] += bsum[blockIdx.x];
  if (i == 0) roff[N_NODES] = N_EDGES;
}

__global__ __launch_bounds__(256) void scatter_k(const int* __restrict__ ei,
                                                 const int* __restrict__ roff,
                                                 int* __restrict__ cursor,
                                                 int* __restrict__ ssrc) {
  int e = blockIdx.x * 256 + threadIdx.x;
  if (e >= N_EDGES) return;
  int dst = ei[N_EDGES + e];
  int pos = roff[dst] + atomicAdd(&cursor[dst], 1);
  ssrc[pos] = ei[e];
}

// ====== degree counting sort: nodeord pairs similar-degree nodes ==========
__global__ __launch_bounds__(256) void dsort_hist(const int* __restrict__ roff,
                                                  int* __restrict__ dh) {
  int n = blockIdx.x * 256 + threadIdx.x;
  if (n < N_NODES) {
    int d = roff[n + 1] - roff[n];
    atomicAdd(&dh[d > 255 ? 255 : d], 1);
  }
}
__global__ __launch_bounds__(256) void dsort_scan(const int* __restrict__ dh,
                                                  int* __restrict__ dcur) {
  __shared__ int s[256];
  int i = threadIdx.x;
  int v = dh[i];
  s[i] = v;
  __syncthreads();
  #pragma unroll
  for (int o = 1; o < 256; o <<= 1) {
    int t = (i >= o) ? s[i - o] : 0;
    __syncthreads();
    s[i] += t;
    __syncthreads();
  }
  dcur[i] = s[i] - v;   // exclusive start; doubles as cursor
}
__global__ __launch_bounds__(256) void dsort_scatter(const int* __restrict__ roff,
                                                     int* __restrict__ dcur,
                                                     int* __restrict__ nodeord) {
  int n = blockIdx.x * 256 + threadIdx.x;
  if (n >= N_NODES) return;
  int d = roff[n + 1] - roff[n];
  int pos = atomicAdd(&dcur[d > 255 ? 255 : d], 1);
  nodeord[pos] = n;
}

// ======== weight splits: W1T[352][128] hi/lo (cols 320+ = fused edot) ======
__global__ __launch_bounds__(256) void conv_w(const float* __restrict__ W1,
                                              const float* __restrict__ W2,
                                              unsigned short* __restrict__ W1hT,
                                              unsigned short* __restrict__ W1lT,
                                              unsigned short* __restrict__ W2hT,
                                              unsigned short* __restrict__ W2lT) {
  int i = blockIdx.x * 256 + threadIdx.x;
  if (i < IN_CH * HC) {                 // i = n*128 + k
    int n = i >> 7, k = i & 127;
    float v = W1[(size_t)k * HC + n];
    unsigned short h = f2bf(v);
    W1hT[i] = h; W1lT[i] = f2bf(v - bf2f(h));
  } else {
    int j = i - IN_CH * HC;
    if (j < OUT_CH * HC) {              // j = c*320 + k
      int c = j / HC, k = j - c * HC;
      float v = W2[(size_t)k * OUT_CH + c];
      unsigned short h = f2bf(v);
      W2hT[j] = h; W2lT[j] = f2bf(v - bf2f(h));
    }
  }
}

__global__ __launch_bounds__(256) void conv_wa(const float* __restrict__ W1,
                                               const float* __restrict__ a_src1,
                                               const float* __restrict__ a_dst1,
                                               unsigned short* __restrict__ W1hT,
                                               unsigned short* __restrict__ W1lT) {
  int i = blockIdx.x * 256 + threadIdx.x;   // i = j*128 + k, j=0..31
  if (i >= 32 * IN_CH) return;
  int j = i >> 7, k = i & 127;
  float v = 0.f;
  if (j < 20) {
    int head = (j < 10) ? j : (j - 10);
    const float* a = (j < 10) ? (a_src1 + head * OUT_CH) : (a_dst1 + head * OUT_CH);
    const float* wrow = W1 + (size_t)k * HC + head * OUT_CH;
    #pragma unroll
    for (int c = 0; c < OUT_CH; c++) v += wrow[c] * a[c];
  }
  unsigned short h = f2bf(v);
  W1hT[(size_t)(HC + j) * IN_CH + k] = h;
  W1lT[(size_t)(HC + j) * IN_CH + k] = f2bf(v - bf2f(h));
}

// == GEMM1 (fused X-split + fused edot1): h1b = X@W1 (bf16); es/ed = X@W1a ==
__global__ __launch_bounds__(256) void gemm1_mfma(const float* __restrict__ X,
                                                  const unsigned short* __restrict__ WhT,
                                                  const unsigned short* __restrict__ WlT,
                                                  unsigned short* __restrict__ Hb,
                                                  float* __restrict__ es,
                                                  float* __restrict__ ed) {
  const int wave = threadIdx.x >> 6;
  const int lane = threadIdx.x & 63;
  const int row0 = blockIdx.x * 64 + wave * 16;
  const int r = lane & 15;
  const int kg = lane >> 4;                          // 0..3
  int arow = row0 + r; if (arow >= N_NODES) arow = N_NODES - 1;
  const float* xrow = X + (size_t)arow * IN_CH + kg * 8;
  const unsigned short* wb = WhT + (size_t)r * IN_CH + kg * 8;   // col-tile 0
  const unsigned short* lb = WlT + (size_t)r * IN_CH + kg * 8;
  f32x4 acc[22];
  #pragma unroll
  for (int c = 0; c < 22; c++) acc[c] = f32x4{0.f, 0.f, 0.f, 0.f};
  #pragma unroll
  for (int k0 = 0; k0 < IN_CH; k0 += 32) {
    float4 u = *reinterpret_cast<const float4*>(xrow + k0);
    float4 w = *reinterpret_cast<const float4*>(xrow + k0 + 4);
    float uv0 = u.x, uv1 = u.y, uv2 = u.z, uv3 = u.w;
    float uv4 = w.x, uv5 = w.y, uv6 = w.z, uv7 = w.w;
    bf16x8 ah, al;
    unsigned short hh;
    hh = f2bf(uv0); ah[0] = (short)hh; al[0] = (short)f2bf(uv0 - bf2f(hh));
    hh = f2bf(uv1); ah[1] = (short)hh; al[1] = (short)f2bf(uv1 - bf2f(hh));
    hh = f2bf(uv2); ah[2] = (short)hh; al[2] = (short)f2bf(uv2 - bf2f(hh));
    hh = f2bf(uv3); ah[3] = (short)hh; al[3] = (short)f2bf(uv3 - bf2f(hh));
    hh = f2bf(uv4); ah[4] = (short)hh; al[4] = (short)f2bf(uv4 - bf2f(hh));
    hh = f2bf(uv5); ah[5] = (short)hh; al[5] = (short)f2bf(uv5 - bf2f(hh));
    hh = f2bf(uv6); ah[6] = (short)hh; al[6] = (short)f2bf(uv6 - bf2f(hh));
    hh = f2bf(uv7); ah[7] = (short)hh; al[7] = (short)f2bf(uv7 - bf2f(hh));
    #pragma unroll
    for (int c = 0; c < 22; c++) {
      bf16x8 bh = *reinterpret_cast<const bf16x8*>(wb + (size_t)c * 16 * IN_CH + k0);
      bf16x8 bl = *reinterpret_cast<const bf16x8*>(lb + (size_t)c * 16 * IN_CH + k0);
      acc[c] = __builtin_amdgcn_mfma_f32_16x16x32_bf16(ah, bh, acc[c], 0, 0, 0);
      acc[c] = __builtin_amdgcn_mfma_f32_16x16x32_bf16(ah, bl, acc[c], 0, 0, 0);
      acc[c] = __builtin_amdgcn_mfma_f32_16x16x32_bf16(al, bh, acc[c], 0, 0, 0);
    }
  }
  const int crow0 = row0 + kg * 4;
  #pragma unroll
  for (int c = 0; c < 20; c++) {
    const int ccol = c * 16 + r;
    #pragma unroll
    for (int t = 0; t < 4; t++) {
      int rr = crow0 + t;
      if (rr < N_NODES) Hb[(size_t)rr * HC + ccol] = f2bf(acc[c][t]);
    }
  }
  #pragma unroll
  for (int t = 0; t < 4; t++) {
    int rr = crow0 + t;
    if (rr < N_NODES) {
      float v20 = acc[20][t];
      if (r < 10) es[rr * 10 + r] = v20;
      else        ed[rr * 10 + (r - 10)] = v20;
      if (r < 4)  ed[rr * 10 + 6 + r] = acc[21][t];
    }
  }
}

// === GEMM2 + fused edot2: h2[N,32](f32) = act @ W2 ; es/ed = h2 . a_{s,d} ==
__global__ __launch_bounds__(256) void gemm2_mfma(const unsigned short* __restrict__ Ah,
                                                  const unsigned short* __restrict__ Al,
                                                  const unsigned short* __restrict__ WhT,
                                                  const unsigned short* __restrict__ WlT,
                                                  const float* __restrict__ a_src2,
                                                  const float* __restrict__ a_dst2,
                                                  float* __restrict__ H,
                                                  float* __restrict__ es,
                                                  float* __restrict__ ed) {
  const int wave = threadIdx.x >> 6;
  const int lane = threadIdx.x & 63;
  const int row0 = blockIdx.x * 64 + wave * 16;
  const int r = lane & 15;
  const int kg = lane >> 4;
  int arow = row0 + r; if (arow >= N_NODES) arow = N_NODES - 1;
  const unsigned short* ah_p = Ah + (size_t)arow * HC + kg * 8;
  const unsigned short* al_p = Al + (size_t)arow * HC + kg * 8;
  const unsigned short* wb = WhT + (size_t)r * HC + kg * 8;
  const unsigned short* lb = WlT + (size_t)r * HC + kg * 8;
  f32x4 acc[2];
  acc[0] = f32x4{0.f, 0.f, 0.f, 0.f};
  acc[1] = f32x4{0.f, 0.f, 0.f, 0.f};
  #pragma unroll
  for (int k0 = 0; k0 < HC; k0 += 32) {
    bf16x8 ah = *reinterpret_cast<const bf16x8*>(ah_p + k0);
    bf16x8 al = *reinterpret_cast<const bf16x8*>(al_p + k0);
    #pragma unroll
    for (int c = 0; c < 2; c++) {
      bf16x8 bh = *reinterpret_cast<const bf16x8*>(wb + (size_t)c * 16 * HC + k0);
      bf16x8 bl = *reinterpret_cast<const bf16x8*>(lb + (size_t)c * 16 * HC + k0);
      acc[c] = __builtin_amdgcn_mfma_f32_16x16x32_bf16(ah, bh, acc[c], 0, 0, 0);
      acc[c] = __builtin_amdgcn_mfma_f32_16x16x32_bf16(ah, bl, acc[c], 0, 0, 0);
      acc[c] = __builtin_amdgcn_mfma_f32_16x16x32_bf16(al, bh, acc[c], 0, 0, 0);
    }
  }
  const int crow0 = row0 + kg * 4;
  #pragma unroll
  for (int c = 0; c < 2; c++) {
    const int ccol = c * 16 + r;
    #pragma unroll
    for (int t = 0; t < 4; t++) {
      int rr = crow0 + t;
      if (rr < N_NODES) H[(size_t)rr * OUT_CH + ccol] = acc[c][t];
    }
  }
  const float as0 = a_src2[r], as1 = a_src2[16 + r];
  const float ad0 = a_dst2[r], ad1 = a_dst2[16 + r];
  float pe[4], pd[4];
  #pragma unroll
  for (int t = 0; t < 4; t++) {
    pe[t] = acc[0][t] * as0 + acc[1][t] * as1;
    pd[t] = acc[0][t] * ad0 + acc[1][t] * ad1;
  }
  #pragma unroll
  for (int o = 1; o < 16; o <<= 1) {
    #pragma unroll
    for (int t = 0; t < 4; t++) {
      pe[t] += __shfl_xor(pe[t], o);
      pd[t] += __shfl_xor(pd[t], o);
    }
  }
  if (r == 0) {
    #pragma unroll
    for (int t = 0; t < 4; t++) {
      int rr = crow0 + t;
      if (rr < N_NODES) { es[rr] = pe[t]; ed[rr] = pd[t]; }
    }
  }
}

// ------ layer-1 aggregation: HALF-WAVE per node, degree-paired -------------
// Wave handles nodes nodeord[2w] (lanes 0-31) and nodeord[2w+1] (lanes 32-63).
// Tiled: 32 edges/tile; phase-1 fills LDS (ex[10]+byteoff) per half; gather
// runs 1 edge/iter/half, each lane covering 10 cols (8 main + 2 tail).
// deg=0 falls through (acc=0, dm=0 -> 0*1e16+b). Sorted pairing => equal deg.
__global__ __launch_bounds__(256) void agg1(const int* __restrict__ roff,
                                            const int* __restrict__ ssrc,
                                            const float* __restrict__ es,
                                            const float* __restrict__ ed,
                                            const unsigned short* __restrict__ h1b,
                                            const float* __restrict__ b1,
                                            const int* __restrict__ nodeord,
                                            unsigned short* __restrict__ acth,
                                            unsigned short* __restrict__ actl) {
  __shared__ float lds[4][2][32][11];
  const int wid = blockIdx.x * 4 + (threadIdx.x >> 6);
  const int wslot = threadIdx.x >> 6;
  const int lane = threadIdx.x & 63;
  const int half = lane >> 5;
  const int lc = lane & 31;
  const int n = nodeord[2 * wid + half];      // grid sized so always valid
  const int beg = roff[n];
  const int deg = roff[n + 1] - beg;
  const int degmax = max(deg, __shfl_xor(deg, 32));

  const int hm = lc >> 2;            // head of main cols 8lc..8lc+7
  const int ht = 8 + (lc >> 4);      // head of tail cols 256+2lc..+1
  float accm[8] = {};
  float acct0 = 0.f, acct1 = 0.f, dm = 0.f, dt = 0.f;
  const char* basem = reinterpret_cast<const char*>(h1b + 8 * lc);
  const char* baset = reinterpret_cast<const char*>(h1b + 256 + 2 * lc);

  for (int t0 = 0; t0 < degmax; t0 += 32) {
    // phase 1 (this tile): lane lc owns edge t0+lc of its half's node
    const int e = t0 + lc;
    const bool act = (e < deg);
    const int src = act ? ssrc[beg + e] : 0;
    #pragma unroll
    for (int p = 0; p < 5; p++) {
      float2 edp = *reinterpret_cast<const float2*>(ed + n * 10 + 2 * p);
      float2 esp = *reinterpret_cast<const float2*>(es + src * 10 + 2 * p);
      lds[wslot][half][lc][2 * p]     = act ? expf(leaky(esp.x + edp.x)) : 0.f;
      lds[wslot][half][lc][2 * p + 1] = act ? expf(leaky(esp.y + edp.y)) : 0.f;
    }
    lds[wslot][half][lc][10] = __int_as_float(src * (HC * 2));
    // gather (wave-synchronous LDS visibility within the wave)
    int cnt = deg - t0;
    cnt = cnt < 0 ? 0 : (cnt > 32 ? 32 : cnt);
    const int cntm = max(cnt, __shfl_xor(cnt, 32));
    for (int j = 0; j < cntm; j++) {
      int off = __float_as_int(lds[wslot][half][j][10]);
      float cm = lds[wslot][half][j][hm];
      float ct = lds[wslot][half][j][ht];
      uint4 v = *reinterpret_cast<const uint4*>(basem + off);
      unsigned tt = *reinterpret_cast<const unsigned*>(baset + off);
      unsigned w0 = v.x, w1 = v.y, w2 = v.z, w3 = v.w;
      accm[0] = fmaf(bflo(w0), cm, accm[0]);
      accm[1] = fmaf(bfhi(w0), cm, accm[1]);
      accm[2] = fmaf(bflo(w1), cm, accm[2]);
      accm[3] = fmaf(bfhi(w1), cm, accm[3]);
      accm[4] = fmaf(bflo(w2), cm, accm[4]);
      accm[5] = fmaf(bfhi(w2), cm, accm[5]);
      accm[6] = fmaf(bflo(w3), cm, accm[6]);
      accm[7] = fmaf(bfhi(w3), cm, accm[7]);
      acct0 = fmaf(bflo(tt), ct, acct0);
      acct1 = fmaf(bfhi(tt), ct, acct1);
      dm += cm;
      dt += ct;
    }
  }

  // epilogue: all 64 lanes active (each half writes its node's 320 cols)
  const float invm = 1.f / (dm + 1e-16f);
  const float invt = 1.f / (dt + 1e-16f);
  const size_t base = (size_t)n * HC;
  usx4 sh0, sl0, sh1, sl1;
  float vv;
  unsigned short hh;
  vv = elu(accm[0] * invm + b1[8 * lc + 0]); hh = f2bf(vv); sh0[0] = hh; sl0[0] = f2bf(vv - bf2f(hh));
  vv = elu(accm[1] * invm + b1[8 * lc + 1]); hh = f2bf(vv); sh0[1] = hh; sl0[1] = f2bf(vv - bf2f(hh));
  vv = elu(accm[2] * invm + b1[8 * lc + 2]); hh = f2bf(vv); sh0[2] = hh; sl0[2] = f2bf(vv - bf2f(hh));
  vv = elu(accm[3] * invm + b1[8 * lc + 3]); hh = f2bf(vv); sh0[3] = hh; sl0[3] = f2bf(vv - bf2f(hh));
  vv = elu(accm[4] * invm + b1[8 * lc + 4]); hh = f2bf(vv); sh1[0] = hh; sl1[0] = f2bf(vv - bf2f(hh));
  vv = elu(accm[5] * invm + b1[8 * lc + 5]); hh = f2bf(vv); sh1[1] = hh; sl1[1] = f2bf(vv - bf2f(hh));
  vv = elu(accm[6] * invm + b1[8 * lc + 6]); hh = f2bf(vv); sh1[2] = hh; sl1[2] = f2bf(vv - bf2f(hh));
  vv = elu(accm[7] * invm + b1[8 * lc + 7]); hh = f2bf(vv); sh1[3] = hh; sl1[3] = f2bf(vv - bf2f(hh));
  *reinterpret_cast<usx4*>(acth + base + 8 * lc) = sh0;
  *reinterpret_cast<usx4*>(acth + base + 8 * lc + 4) = sh1;
  *reinterpret_cast<usx4*>(actl + base + 8 * lc) = sl0;
  *reinterpret_cast<usx4*>(actl + base + 8 * lc + 4) = sl1;
  unsigned tph, tpl;
  unsigned short h0, h1v, l0, l1v;
  vv = elu(acct0 * invt + b1[256 + 2 * lc + 0]); h0 = f2bf(vv); l0 = f2bf(vv - bf2f(h0));
  vv = elu(acct1 * invt + b1[256 + 2 * lc + 1]); h1v = f2bf(vv); l1v = f2bf(vv - bf2f(h1v));
  tph = (unsigned)h0 | ((unsigned)h1v << 16);
  tpl = (unsigned)l0 | ((unsigned)l1v << 16);
  *reinterpret_cast<unsigned*>(acth + base + 256 + 2 * lc) = tph;
  *reinterpret_cast<unsigned*>(actl + base + 256 + 2 * lc) = tpl;
}

// ------ layer-2 aggregation: HALF-WAVE per node, tiled, fused pool ---------
__global__ __launch_bounds__(256) void agg2(const int* __restrict__ roff,
                                            const int* __restrict__ ssrc,
                                            const float* __restrict__ es,
                                            const float* __restrict__ ed,
                                            const float* __restrict__ h2,
                                            const float* __restrict__ b2,
                                            const int* __restrict__ batch,
                                            const int* __restrict__ nodeord,
                                            unsigned* __restrict__ pooled) {
  __shared__ float lds[4][2][32][2];
  const int wid = blockIdx.x * 4 + (threadIdx.x >> 6);
  const int wslot = threadIdx.x >> 6;
  const int lane = threadIdx.x & 63;
  const int half = lane >> 5;
  const int lc = lane & 31;
  const int n = nodeord[2 * wid + half];
  const int beg = roff[n];
  const int deg = roff[n + 1] - beg;
  const int degmax = max(deg, __shfl_xor(deg, 32));
  const float edv = ed[n];

  float acc = 0.f, dacc = 0.f;
  const char* baseh = reinterpret_cast<const char*>(h2 + lc);

  for (int t0 = 0; t0 < degmax; t0 += 32) {
    const int e = t0 + lc;
    const bool act = (e < deg);
    const int src = act ? ssrc[beg + e] : 0;
    lds[wslot][half][lc][0] = act ? expf(leaky(es[src] + edv)) : 0.f;
    lds[wslot][half][lc][1] = __int_as_float(src * (OUT_CH * 4));
    int cnt = deg - t0;
    cnt = cnt < 0 ? 0 : (cnt > 32 ? 32 : cnt);
    const int cntm = max(cnt, __shfl_xor(cnt, 32));
    for (int j = 0; j < cntm; j++) {
      int off = __float_as_int(lds[wslot][half][j][1]);
      float cj = lds[wslot][half][j][0];
      acc = fmaf(*reinterpret_cast<const float*>(baseh + off), cj, acc);
      dacc += cj;
    }
  }
  float v = elu(acc / (dacc + 1e-16f) + b2[lc]);
  atomicMax(&pooled[batch[n] * OUT_CH + lc], fmap(v));
}

// -------- final: out[g,c] = relu(pooled[g,:] @ fc_w[:,c] + fc_b[c]) --------
__global__ __launch_bounds__(256) void final_k(const unsigned* __restrict__ pooled,
                                               const float* __restrict__ fc_w,
                                               const float* __restrict__ fc_b,
                                               float* __restrict__ out) {
  int idx = blockIdx.x * 256 + threadIdx.x;
  if (idx >= N_GRAPHS * OUT_CH) return;
  int g = idx >> 5, c = idx & 31;
  float s = fc_b[c];
  #pragma unroll
  for (int k = 0; k < OUT_CH; k++) {
    unsigned u = pooled[g * OUT_CH + k];
    float p = (u == 0u) ? 0.f : funmap(u);
    s += p * fc_w[k * OUT_CH + c];
  }
  out[idx] = s > 0.f ? s : 0.f;
}

extern "C" void kernel_launch(void* const* d_in, const int* in_sizes, int n_in,
                              void* d_out, int out_size, void* d_ws, size_t ws_size,
                              hipStream_t stream) {
  const float* x      = (const float*)d_in[0];
  const int*   ei     = (const int*)d_in[1];
  const int*   batch  = (const int*)d_in[2];
  const float* W1     = (const float*)d_in[4];
  const float* a_src1 = (const float*)d_in[5];
  const float* a_dst1 = (const float*)d_in[6];
  const float* b1     = (const float*)d_in[7];
  const float* W2     = (const float*)d_in[8];
  const float* a_src2 = (const float*)d_in[9];
  const float* a_dst2 = (const float*)d_in[10];
  const float* b2     = (const float*)d_in[11];
  const float* fc_w   = (const float*)d_in[12];
  const float* fc_b   = (const float*)d_in[13];
  float* out = (float*)d_out;

  // ---- workspace layout (<= 136 MB, phase-aliased) ----
  // A [0,64M): h1b bf16 32MB; h2 f32 aliases head after agg1;
  //            nodeord/dh/dcur at +40M (untouched by h1b/h2).
  // B [64M,128M): act_h|act_l (64M)
  // S [128M,136M): CSR + es/ed + pooled; W-splits alias dead deg/cursor
  char* ws = (char*)d_ws;
  unsigned short* h1b = (unsigned short*)(ws);              // 32 MB
  float* h2   = (float*)(ws);                               // after agg1
  int*   nodeord = (int*)(ws + 40000000);                   // 200 KB
  int*   dh      = (int*)(ws + 40200064);                   // 1 KB
  int*   dcur    = (int*)(ws + 40201088);                   // 1 KB
  unsigned short* acth = (unsigned short*)(ws + 64000000);  // 32 MB
  unsigned short* actl = (unsigned short*)(ws + 96000000);  // 32 MB
  char*  S    = ws + 128000000;
  int*   ssrc   = (int*)(S);                  // 3.2 MB
  int*   roff   = (int*)(S + 3200000);        // 200,004 B
  int*   deg    = (int*)(S + 3400064);        // 200,000 B (dead after scan)
  int*   cursor = (int*)(S + 3600064);        // 200,000 B (dead after scatter)
  unsigned short* W1hT = (unsigned short*)(S + 3400064);                // 90,112 B
  unsigned short* W1lT = (unsigned short*)(S + 3400064 + 90112);        // 90,112 B
  unsigned short* W2hT = (unsigned short*)(S + 3400064 + 180224);       // 20,480 B
  unsigned short* W2lT = (unsigned short*)(S + 3400064 + 200704);       // 20,480 B
  float* es1    = (float*)(S + 3800064);      // 2 MB
  float* ed1    = (float*)(S + 5800064);      // 2 MB
  int*   bsum   = (int*)(S + 7800064);        // 784 B
  unsigned* pooled = (unsigned*)(S + 7801600);// 64 KB
  float* es2 = es1; float* ed2 = ed1;         // dead after agg1

  // ---- CSR build ----
  hipMemsetAsync(deg, 0, (size_t)N_NODES * 4, stream);
  hipMemsetAsync(cursor, 0, (size_t)N_NODES * 4, stream);
  hist_k   <<<(N_EDGES + 255) / 256, 256, 0, stream>>>(ei, deg);
  scan_blk <<<NBLK_SCAN, 256, 0, stream>>>(deg, roff, bsum);
  scan_top <<<1, 256, 0, stream>>>(bsum);
  scan_add <<<NBLK_SCAN, 256, 0, stream>>>(roff, bsum);
  scatter_k<<<(N_EDGES + 255) / 256, 256, 0, stream>>>(ei, roff, cursor, ssrc);

  // ---- degree counting sort (pairs similar-degree nodes for agg) ----
  hipMemsetAsync(dh, 0, 1024, stream);
  dsort_hist   <<<NBLK_SCAN, 256, 0, stream>>>(roff, dh);
  dsort_scan   <<<1, 256, 0, stream>>>(dh, dcur);
  dsort_scatter<<<NBLK_SCAN, 256, 0, stream>>>(roff, dcur, nodeord);

  // ---- weight splits (AFTER scatter: alias dead deg/cursor) ----
  conv_w<<<(IN_CH * HC + OUT_CH * HC + 255) / 256, 256, 0, stream>>>(
      W1, W2, W1hT, W1lT, W2hT, W2lT);
  conv_wa<<<(32 * IN_CH + 255) / 256, 256, 0, stream>>>(
      W1, a_src1, a_dst1, W1hT, W1lT);

  // ---- layer 1 (es/ed fused into gemm1) ----
  gemm1_mfma<<<(N_NODES + 63) / 64, 256, 0, stream>>>(x, W1hT, W1lT, h1b, es1, ed1);
  agg1 <<<N_NODES / 8, 256, 0, stream>>>(roff, ssrc, es1, ed1, h1b, b1, nodeord,
                                         acth, actl);

  // ---- layer 2 (edot2 fused into gemm2) ----
  hipMemsetAsync(pooled, 0, (size_t)N_GRAPHS * OUT_CH * 4, stream);
  gemm2_mfma<<<(N_NODES + 63) / 64, 256, 0, stream>>>(acth, actl, W2hT, W2lT,
                                                      a_src2, a_dst2, h2, es2, ed2);
  agg2 <<<N_NODES / 8, 256, 0, stream>>>(roff, ssrc, es2, ed2, h2, b2, batch, nodeord,
                                         pooled);
  final_k<<<(N_GRAPHS * OUT_CH + 255) / 256, 256, 0, stream>>>(pooled, fc_w, fc_b, out);
}

// Round 20
// 356.081 us; speedup vs baseline: 1.7361x; 1.7361x over previous
//
#include <hip/hip_runtime.h>

#define N_NODES 50000
#define N_EDGES 800000
#define IN_CH   128
#define OUT_CH  32
#define HEADS   10
#define HC      320           // HEADS*OUT_CH
#define N_GRAPHS 512
#define NEG_SLOPE 0.2f
#define NBLK_SCAN 196         // ceil(50000/256)

typedef __attribute__((ext_vector_type(8))) short bf16x8;   // 8 bf16 in 4 VGPRs
typedef __attribute__((ext_vector_type(4))) float f32x4;
typedef __attribute__((ext_vector_type(4))) unsigned short usx4;  // native 8B vec

__device__ __forceinline__ unsigned fmap(float f) {
  unsigned u = __float_as_uint(f);
  return (u & 0x80000000u) ? ~u : (u | 0x80000000u);
}
__device__ __forceinline__ float funmap(unsigned u) {
  u = (u & 0x80000000u) ? (u ^ 0x80000000u) : ~u;
  return __uint_as_float(u);
}
__device__ __forceinline__ float leaky(float a) {
  return a > 0.f ? a : NEG_SLOPE * a;
}
__device__ __forceinline__ unsigned short f2bf(float f) {
  unsigned u = __float_as_uint(f);
  return (unsigned short)((u + 0x7FFFu + ((u >> 16) & 1u)) >> 16);
}
__device__ __forceinline__ float bf2f(unsigned short b) {
  return __uint_as_float(((unsigned)b) << 16);
}
__device__ __forceinline__ float bflo(unsigned u) { return __uint_as_float(u << 16); }
__device__ __forceinline__ float bfhi(unsigned u) { return __uint_as_float(u & 0xFFFF0000u); }
__device__ __forceinline__ float elu(float v) {
  return v > 0.f ? v : expm1f(v);
}

// ============================ CSR construction =============================
__global__ __launch_bounds__(256) void hist_k(const int* __restrict__ ei,
                                              int* __restrict__ deg) {
  int e = blockIdx.x * 256 + threadIdx.x;
  if (e < N_EDGES) atomicAdd(&deg[ei[N_EDGES + e]], 1);
}

__global__ __launch_bounds__(256) void scan_blk(const int* __restrict__ deg,
                                                int* __restrict__ roff,
                                                int* __restrict__ bsum) {
  __shared__ int s[256];
  int i = blockIdx.x * 256 + threadIdx.x;
  int v = (i < N_NODES) ? deg[i] : 0;
  s[threadIdx.x] = v;
  __syncthreads();
  #pragma unroll
  for (int o = 1; o < 256; o <<= 1) {
    int t = (threadIdx.x >= o) ? s[threadIdx.x - o] : 0;
    __syncthreads();
    s[threadIdx.x] += t;
    __syncthreads();
  }
  if (i < N_NODES) roff[i] = s[threadIdx.x] - v;   // exclusive
  if (threadIdx.x == 255) bsum[blockIdx.x] = s[255];
}

__global__ __launch_bounds__(256) void scan_top(int* __restrict__ bsum) {
  __shared__ int s[256];
  int i = threadIdx.x;
  int v = (i < NBLK_SCAN) ? bsum[i] : 0;
  s[i] = v;
  __syncthreads();
  #pragma unroll
  for (int o = 1; o < 256; o <<= 1) {
    int t = (i >= o) ? s[i - o] : 0;
    __syncthreads();
    s[i] += t;
    __syncthreads();
  }
  if (i < NBLK_SCAN) bsum[i] = s[i] - v;           // exclusive
}

__global__ __launch_bounds__(256) void scan_add(int* __restrict__ roff,
                                                const int* __restrict__ bsum) {
  int i = blockIdx.x * 256 + threadIdx.x;
  if (i < N_NODES) roff[i] += bsum[blockIdx.x];
  if (i == 0) roff[N_NODES] = N_EDGES;
}

__global__ __launch_bounds__(256) void scatter_k(const int* __restrict__ ei,
                                                 const int* __restrict__ roff,
                                                 int* __restrict__ cursor,
                                                 int* __restrict__ ssrc) {
  int e = blockIdx.x * 256 + threadIdx.x;
  if (e >= N_EDGES) return;
  int dst = ei[N_EDGES + e];
  int pos = roff[dst] + atomicAdd(&cursor[dst], 1);
  ssrc[pos] = ei[e];
}

// ======== weight splits: W1T[352][128] hi/lo (cols 320+ = fused edot) ======
__global__ __launch_bounds__(256) void conv_w(const float* __restrict__ W1,
                                              const float* __restrict__ W2,
                                              unsigned short* __restrict__ W1hT,
                                              unsigned short* __restrict__ W1lT,
                                              unsigned short* __restrict__ W2hT,
                                              unsigned short* __restrict__ W2lT) {
  int i = blockIdx.x * 256 + threadIdx.x;
  if (i < IN_CH * HC) {                 // i = n*128 + k
    int n = i >> 7, k = i & 127;
    float v = W1[(size_t)k * HC + n];
    unsigned short h = f2bf(v);
    W1hT[i] = h; W1lT[i] = f2bf(v - bf2f(h));
  } else {
    int j = i - IN_CH * HC;
    if (j < OUT_CH * HC) {              // j = c*320 + k
      int c = j / HC, k = j - c * HC;
      float v = W2[(size_t)k * OUT_CH + c];
      unsigned short h = f2bf(v);
      W2hT[j] = h; W2lT[j] = f2bf(v - bf2f(h));
    }
  }
}

__global__ __launch_bounds__(256) void conv_wa(const float* __restrict__ W1,
                                               const float* __restrict__ a_src1,
                                               const float* __restrict__ a_dst1,
                                               unsigned short* __restrict__ W1hT,
                                               unsigned short* __restrict__ W1lT) {
  int i = blockIdx.x * 256 + threadIdx.x;   // i = j*128 + k, j=0..31
  if (i >= 32 * IN_CH) return;
  int j = i >> 7, k = i & 127;
  float v = 0.f;
  if (j < 20) {
    int head = (j < 10) ? j : (j - 10);
    const float* a = (j < 10) ? (a_src1 + head * OUT_CH) : (a_dst1 + head * OUT_CH);
    const float* wrow = W1 + (size_t)k * HC + head * OUT_CH;
    #pragma unroll
    for (int c = 0; c < OUT_CH; c++) v += wrow[c] * a[c];
  }
  unsigned short h = f2bf(v);
  W1hT[(size_t)(HC + j) * IN_CH + k] = h;
  W1lT[(size_t)(HC + j) * IN_CH + k] = f2bf(v - bf2f(h));
}

// == GEMM1 (fused X-split + fused edot1): h1b = X@W1 (bf16); es/ed = X@W1a ==
__global__ __launch_bounds__(256) void gemm1_mfma(const float* __restrict__ X,
                                                  const unsigned short* __restrict__ WhT,
                                                  const unsigned short* __restrict__ WlT,
                                                  unsigned short* __restrict__ Hb,
                                                  float* __restrict__ es,
                                                  float* __restrict__ ed) {
  const int wave = threadIdx.x >> 6;
  const int lane = threadIdx.x & 63;
  const int row0 = blockIdx.x * 64 + wave * 16;
  const int r = lane & 15;
  const int kg = lane >> 4;                          // 0..3
  int arow = row0 + r; if (arow >= N_NODES) arow = N_NODES - 1;
  const float* xrow = X + (size_t)arow * IN_CH + kg * 8;
  const unsigned short* wb = WhT + (size_t)r * IN_CH + kg * 8;   // col-tile 0
  const unsigned short* lb = WlT + (size_t)r * IN_CH + kg * 8;
  f32x4 acc[22];
  #pragma unroll
  for (int c = 0; c < 22; c++) acc[c] = f32x4{0.f, 0.f, 0.f, 0.f};
  #pragma unroll
  for (int k0 = 0; k0 < IN_CH; k0 += 32) {
    float4 u = *reinterpret_cast<const float4*>(xrow + k0);
    float4 w = *reinterpret_cast<const float4*>(xrow + k0 + 4);
    float uv0 = u.x, uv1 = u.y, uv2 = u.z, uv3 = u.w;
    float uv4 = w.x, uv5 = w.y, uv6 = w.z, uv7 = w.w;
    bf16x8 ah, al;
    unsigned short hh;
    hh = f2bf(uv0); ah[0] = (short)hh; al[0] = (short)f2bf(uv0 - bf2f(hh));
    hh = f2bf(uv1); ah[1] = (short)hh; al[1] = (short)f2bf(uv1 - bf2f(hh));
    hh = f2bf(uv2); ah[2] = (short)hh; al[2] = (short)f2bf(uv2 - bf2f(hh));
    hh = f2bf(uv3); ah[3] = (short)hh; al[3] = (short)f2bf(uv3 - bf2f(hh));
    hh = f2bf(uv4); ah[4] = (short)hh; al[4] = (short)f2bf(uv4 - bf2f(hh));
    hh = f2bf(uv5); ah[5] = (short)hh; al[5] = (short)f2bf(uv5 - bf2f(hh));
    hh = f2bf(uv6); ah[6] = (short)hh; al[6] = (short)f2bf(uv6 - bf2f(hh));
    hh = f2bf(uv7); ah[7] = (short)hh; al[7] = (short)f2bf(uv7 - bf2f(hh));
    #pragma unroll
    for (int c = 0; c < 22; c++) {
      bf16x8 bh = *reinterpret_cast<const bf16x8*>(wb + (size_t)c * 16 * IN_CH + k0);
      bf16x8 bl = *reinterpret_cast<const bf16x8*>(lb + (size_t)c * 16 * IN_CH + k0);
      acc[c] = __builtin_amdgcn_mfma_f32_16x16x32_bf16(ah, bh, acc[c], 0, 0, 0);
      acc[c] = __builtin_amdgcn_mfma_f32_16x16x32_bf16(ah, bl, acc[c], 0, 0, 0);
      acc[c] = __builtin_amdgcn_mfma_f32_16x16x32_bf16(al, bh, acc[c], 0, 0, 0);
    }
  }
  const int crow0 = row0 + kg * 4;
  #pragma unroll
  for (int c = 0; c < 20; c++) {
    const int ccol = c * 16 + r;
    #pragma unroll
    for (int t = 0; t < 4; t++) {
      int rr = crow0 + t;
      if (rr < N_NODES) Hb[(size_t)rr * HC + ccol] = f2bf(acc[c][t]);
    }
  }
  #pragma unroll
  for (int t = 0; t < 4; t++) {
    int rr = crow0 + t;
    if (rr < N_NODES) {
      float v20 = acc[20][t];
      if (r < 10) es[rr * 10 + r] = v20;
      else        ed[rr * 10 + (r - 10)] = v20;
      if (r < 4)  ed[rr * 10 + 6 + r] = acc[21][t];
    }
  }
}

// === GEMM2 + fused edot2: h2[N,32](f32) = act @ W2 ; es/ed = h2 . a_{s,d} ==
__global__ __launch_bounds__(256) void gemm2_mfma(const unsigned short* __restrict__ Ah,
                                                  const unsigned short* __restrict__ Al,
                                                  const unsigned short* __restrict__ WhT,
                                                  const unsigned short* __restrict__ WlT,
                                                  const float* __restrict__ a_src2,
                                                  const float* __restrict__ a_dst2,
                                                  float* __restrict__ H,
                                                  float* __restrict__ es,
                                                  float* __restrict__ ed) {
  const int wave = threadIdx.x >> 6;
  const int lane = threadIdx.x & 63;
  const int row0 = blockIdx.x * 64 + wave * 16;
  const int r = lane & 15;
  const int kg = lane >> 4;
  int arow = row0 + r; if (arow >= N_NODES) arow = N_NODES - 1;
  const unsigned short* ah_p = Ah + (size_t)arow * HC + kg * 8;
  const unsigned short* al_p = Al + (size_t)arow * HC + kg * 8;
  const unsigned short* wb = WhT + (size_t)r * HC + kg * 8;
  const unsigned short* lb = WlT + (size_t)r * HC + kg * 8;
  f32x4 acc[2];
  acc[0] = f32x4{0.f, 0.f, 0.f, 0.f};
  acc[1] = f32x4{0.f, 0.f, 0.f, 0.f};
  #pragma unroll
  for (int k0 = 0; k0 < HC; k0 += 32) {
    bf16x8 ah = *reinterpret_cast<const bf16x8*>(ah_p + k0);
    bf16x8 al = *reinterpret_cast<const bf16x8*>(al_p + k0);
    #pragma unroll
    for (int c = 0; c < 2; c++) {
      bf16x8 bh = *reinterpret_cast<const bf16x8*>(wb + (size_t)c * 16 * HC + k0);
      bf16x8 bl = *reinterpret_cast<const bf16x8*>(lb + (size_t)c * 16 * HC + k0);
      acc[c] = __builtin_amdgcn_mfma_f32_16x16x32_bf16(ah, bh, acc[c], 0, 0, 0);
      acc[c] = __builtin_amdgcn_mfma_f32_16x16x32_bf16(ah, bl, acc[c], 0, 0, 0);
      acc[c] = __builtin_amdgcn_mfma_f32_16x16x32_bf16(al, bh, acc[c], 0, 0, 0);
    }
  }
  const int crow0 = row0 + kg * 4;
  #pragma unroll
  for (int c = 0; c < 2; c++) {
    const int ccol = c * 16 + r;
    #pragma unroll
    for (int t = 0; t < 4; t++) {
      int rr = crow0 + t;
      if (rr < N_NODES) H[(size_t)rr * OUT_CH + ccol] = acc[c][t];
    }
  }
  const float as0 = a_src2[r], as1 = a_src2[16 + r];
  const float ad0 = a_dst2[r], ad1 = a_dst2[16 + r];
  float pe[4], pd[4];
  #pragma unroll
  for (int t = 0; t < 4; t++) {
    pe[t] = acc[0][t] * as0 + acc[1][t] * as1;
    pd[t] = acc[0][t] * ad0 + acc[1][t] * ad1;
  }
  #pragma unroll
  for (int o = 1; o < 16; o <<= 1) {
    #pragma unroll
    for (int t = 0; t < 4; t++) {
      pe[t] += __shfl_xor(pe[t], o);
      pd[t] += __shfl_xor(pd[t], o);
    }
  }
  if (r == 0) {
    #pragma unroll
    for (int t = 0; t < 4; t++) {
      int rr = crow0 + t;
      if (rr < N_NODES) { es[rr] = pe[t]; ed[rr] = pd[t]; }
    }
  }
}

// ------ layer-1 aggregation: HALF-WAVE per node (adjacent-ID pairing) ------
// Wave handles nodes 2*wid (lanes 0-31) and 2*wid+1 (lanes 32-63).
// Tiled: 32 edges/tile; phase-1 fills LDS (ex[10]+byteoff) per half; gather
// runs 1 edge/iter/half, each lane covering 10 cols (8 main + 2 tail).
// deg=0 falls through (acc=0, dm=0 -> 0*1e16+b).
__global__ __launch_bounds__(256) void agg1(const int* __restrict__ roff,
                                            const int* __restrict__ ssrc,
                                            const float* __restrict__ es,
                                            const float* __restrict__ ed,
                                            const unsigned short* __restrict__ h1b,
                                            const float* __restrict__ b1,
                                            unsigned short* __restrict__ acth,
                                            unsigned short* __restrict__ actl) {
  __shared__ float lds[4][2][32][11];
  const int wid = blockIdx.x * 4 + (threadIdx.x >> 6);
  const int wslot = threadIdx.x >> 6;
  const int lane = threadIdx.x & 63;
  const int half = lane >> 5;
  const int lc = lane & 31;
  const int n = 2 * wid + half;               // grid sized so always < N_NODES
  const int beg = roff[n];
  const int deg = roff[n + 1] - beg;
  const int degmax = max(deg, __shfl_xor(deg, 32));

  const int hm = lc >> 2;            // head of main cols 8lc..8lc+7
  const int ht = 8 + (lc >> 4);      // head of tail cols 256+2lc..+1
  float accm[8] = {};
  float acct0 = 0.f, acct1 = 0.f, dm = 0.f, dt = 0.f;
  const char* basem = reinterpret_cast<const char*>(h1b + 8 * lc);
  const char* baset = reinterpret_cast<const char*>(h1b + 256 + 2 * lc);

  for (int t0 = 0; t0 < degmax; t0 += 32) {
    // phase 1 (this tile): lane lc owns edge t0+lc of its half's node
    const int e = t0 + lc;
    const bool act = (e < deg);
    const int src = act ? ssrc[beg + e] : 0;
    #pragma unroll
    for (int p = 0; p < 5; p++) {
      float2 edp = *reinterpret_cast<const float2*>(ed + n * 10 + 2 * p);
      float2 esp = *reinterpret_cast<const float2*>(es + src * 10 + 2 * p);
      lds[wslot][half][lc][2 * p]     = act ? expf(leaky(esp.x + edp.x)) : 0.f;
      lds[wslot][half][lc][2 * p + 1] = act ? expf(leaky(esp.y + edp.y)) : 0.f;
    }
    lds[wslot][half][lc][10] = __int_as_float(src * (HC * 2));
    // gather (wave-synchronous LDS visibility within the wave)
    int cnt = deg - t0;
    cnt = cnt < 0 ? 0 : (cnt > 32 ? 32 : cnt);
    const int cntm = max(cnt, __shfl_xor(cnt, 32));
    for (int j = 0; j < cntm; j++) {
      int off = __float_as_int(lds[wslot][half][j][10]);
      float cm = lds[wslot][half][j][hm];
      float ct = lds[wslot][half][j][ht];
      uint4 v = *reinterpret_cast<const uint4*>(basem + off);
      unsigned tt = *reinterpret_cast<const unsigned*>(baset + off);
      unsigned w0 = v.x, w1 = v.y, w2 = v.z, w3 = v.w;
      accm[0] = fmaf(bflo(w0), cm, accm[0]);
      accm[1] = fmaf(bfhi(w0), cm, accm[1]);
      accm[2] = fmaf(bflo(w1), cm, accm[2]);
      accm[3] = fmaf(bfhi(w1), cm, accm[3]);
      accm[4] = fmaf(bflo(w2), cm, accm[4]);
      accm[5] = fmaf(bfhi(w2), cm, accm[5]);
      accm[6] = fmaf(bflo(w3), cm, accm[6]);
      accm[7] = fmaf(bfhi(w3), cm, accm[7]);
      acct0 = fmaf(bflo(tt), ct, acct0);
      acct1 = fmaf(bfhi(tt), ct, acct1);
      dm += cm;
      dt += ct;
    }
  }

  // epilogue: all 64 lanes active (each half writes its node's 320 cols)
  const float invm = 1.f / (dm + 1e-16f);
  const float invt = 1.f / (dt + 1e-16f);
  const size_t base = (size_t)n * HC;
  usx4 sh0, sl0, sh1, sl1;
  float vv;
  unsigned short hh;
  vv = elu(accm[0] * invm + b1[8 * lc + 0]); hh = f2bf(vv); sh0[0] = hh; sl0[0] = f2bf(vv - bf2f(hh));
  vv = elu(accm[1] * invm + b1[8 * lc + 1]); hh = f2bf(vv); sh0[1] = hh; sl0[1] = f2bf(vv - bf2f(hh));
  vv = elu(accm[2] * invm + b1[8 * lc + 2]); hh = f2bf(vv); sh0[2] = hh; sl0[2] = f2bf(vv - bf2f(hh));
  vv = elu(accm[3] * invm + b1[8 * lc + 3]); hh = f2bf(vv); sh0[3] = hh; sl0[3] = f2bf(vv - bf2f(hh));
  vv = elu(accm[4] * invm + b1[8 * lc + 4]); hh = f2bf(vv); sh1[0] = hh; sl1[0] = f2bf(vv - bf2f(hh));
  vv = elu(accm[5] * invm + b1[8 * lc + 5]); hh = f2bf(vv); sh1[1] = hh; sl1[1] = f2bf(vv - bf2f(hh));
  vv = elu(accm[6] * invm + b1[8 * lc + 6]); hh = f2bf(vv); sh1[2] = hh; sl1[2] = f2bf(vv - bf2f(hh));
  vv = elu(accm[7] * invm + b1[8 * lc + 7]); hh = f2bf(vv); sh1[3] = hh; sl1[3] = f2bf(vv - bf2f(hh));
  *reinterpret_cast<usx4*>(acth + base + 8 * lc) = sh0;
  *reinterpret_cast<usx4*>(acth + base + 8 * lc + 4) = sh1;
  *reinterpret_cast<usx4*>(actl + base + 8 * lc) = sl0;
  *reinterpret_cast<usx4*>(actl + base + 8 * lc + 4) = sl1;
  unsigned tph, tpl;
  unsigned short h0, h1v, l0, l1v;
  vv = elu(acct0 * invt + b1[256 + 2 * lc + 0]); h0 = f2bf(vv); l0 = f2bf(vv - bf2f(h0));
  vv = elu(acct1 * invt + b1[256 + 2 * lc + 1]); h1v = f2bf(vv); l1v = f2bf(vv - bf2f(h1v));
  tph = (unsigned)h0 | ((unsigned)h1v << 16);
  tpl = (unsigned)l0 | ((unsigned)l1v << 16);
  *reinterpret_cast<unsigned*>(acth + base + 256 + 2 * lc) = tph;
  *reinterpret_cast<unsigned*>(actl + base + 256 + 2 * lc) = tpl;
}

// ------ layer-2 aggregation: HALF-WAVE per node, tiled, fused pool ---------
__global__ __launch_bounds__(256) void agg2(const int* __restrict__ roff,
                                            const int* __restrict__ ssrc,
                                            const float* __restrict__ es,
                                            const float* __restrict__ ed,
                                            const float* __restrict__ h2,
                                            const float* __restrict__ b2,
                                            const int* __restrict__ batch,
                                            unsigned* __restrict__ pooled) {
  __shared__ float lds[4][2][32][2];
  const int wid = blockIdx.x * 4 + (threadIdx.x >> 6);
  const int wslot = threadIdx.x >> 6;
  const int lane = threadIdx.x & 63;
  const int half = lane >> 5;
  const int lc = lane & 31;
  const int n = 2 * wid + half;
  const int beg = roff[n];
  const int deg = roff[n + 1] - beg;
  const int degmax = max(deg, __shfl_xor(deg, 32));
  const float edv = ed[n];

  float acc = 0.f, dacc = 0.f;
  const char* baseh = reinterpret_cast<const char*>(h2 + lc);

  for (int t0 = 0; t0 < degmax; t0 += 32) {
    const int e = t0 + lc;
    const bool act = (e < deg);
    const int src = act ? ssrc[beg + e] : 0;
    lds[wslot][half][lc][0] = act ? expf(leaky(es[src] + edv)) : 0.f;
    lds[wslot][half][lc][1] = __int_as_float(src * (OUT_CH * 4));
    int cnt = deg - t0;
    cnt = cnt < 0 ? 0 : (cnt > 32 ? 32 : cnt);
    const int cntm = max(cnt, __shfl_xor(cnt, 32));
    for (int j = 0; j < cntm; j++) {
      int off = __float_as_int(lds[wslot][half][j][1]);
      float cj = lds[wslot][half][j][0];
      acc = fmaf(*reinterpret_cast<const float*>(baseh + off), cj, acc);
      dacc += cj;
    }
  }
  float v = elu(acc / (dacc + 1e-16f) + b2[lc]);
  atomicMax(&pooled[batch[n] * OUT_CH + lc], fmap(v));
}

// -------- final: out[g,c] = relu(pooled[g,:] @ fc_w[:,c] + fc_b[c]) --------
__global__ __launch_bounds__(256) void final_k(const unsigned* __restrict__ pooled,
                                               const float* __restrict__ fc_w,
                                               const float* __restrict__ fc_b,
                                               float* __restrict__ out) {
  int idx = blockIdx.x * 256 + threadIdx.x;
  if (idx >= N_GRAPHS * OUT_CH) return;
  int g = idx >> 5, c = idx & 31;
  float s = fc_b[c];
  #pragma unroll
  for (int k = 0; k < OUT_CH; k++) {
    unsigned u = pooled[g * OUT_CH + k];
    float p = (u == 0u) ? 0.f : funmap(u);
    s += p * fc_w[k * OUT_CH + c];
  }
  out[idx] = s > 0.f ? s : 0.f;
}

extern "C" void kernel_launch(void* const* d_in, const int* in_sizes, int n_in,
                              void* d_out, int out_size, void* d_ws, size_t ws_size,
                              hipStream_t stream) {
  const float* x      = (const float*)d_in[0];
  const int*   ei     = (const int*)d_in[1];
  const int*   batch  = (const int*)d_in[2];
  const float* W1     = (const float*)d_in[4];
  const float* a_src1 = (const float*)d_in[5];
  const float* a_dst1 = (const float*)d_in[6];
  const float* b1     = (const float*)d_in[7];
  const float* W2     = (const float*)d_in[8];
  const float* a_src2 = (const float*)d_in[9];
  const float* a_dst2 = (const float*)d_in[10];
  const float* b2     = (const float*)d_in[11];
  const float* fc_w   = (const float*)d_in[12];
  const float* fc_b   = (const float*)d_in[13];
  float* out = (float*)d_out;

  // ---- workspace layout (<= 136 MB, phase-aliased) ----
  // A [0,64M): h1b bf16 32MB; h2 f32 aliases head after agg1
  // B [64M,128M): act_h|act_l (64M)
  // S [128M,136M): CSR + es/ed + pooled; W-splits alias dead deg/cursor
  char* ws = (char*)d_ws;
  unsigned short* h1b = (unsigned short*)(ws);              // 32 MB
  float* h2   = (float*)(ws);                               // after agg1
  unsigned short* acth = (unsigned short*)(ws + 64000000);  // 32 MB
  unsigned short* actl = (unsigned short*)(ws + 96000000);  // 32 MB
  char*  S    = ws + 128000000;
  int*   ssrc   = (int*)(S);                  // 3.2 MB
  int*   roff   = (int*)(S + 3200000);        // 200,004 B
  int*   deg    = (int*)(S + 3400064);        // 200,000 B (dead after scan)
  int*   cursor = (int*)(S + 3600064);        // 200,000 B (dead after scatter)
  unsigned short* W1hT = (unsigned short*)(S + 3400064);                // 90,112 B
  unsigned short* W1lT = (unsigned short*)(S + 3400064 + 90112);        // 90,112 B
  unsigned short* W2hT = (unsigned short*)(S + 3400064 + 180224);       // 20,480 B
  unsigned short* W2lT = (unsigned short*)(S + 3400064 + 200704);       // 20,480 B
  float* es1    = (float*)(S + 3800064);      // 2 MB
  float* ed1    = (float*)(S + 5800064);      // 2 MB
  int*   bsum   = (int*)(S + 7800064);        // 784 B
  unsigned* pooled = (unsigned*)(S + 7801600);// 64 KB
  float* es2 = es1; float* ed2 = ed1;         // dead after agg1

  // ---- CSR build ----
  hipMemsetAsync(deg, 0, (size_t)N_NODES * 4, stream);
  hipMemsetAsync(cursor, 0, (size_t)N_NODES * 4, stream);
  hist_k   <<<(N_EDGES + 255) / 256, 256, 0, stream>>>(ei, deg);
  scan_blk <<<NBLK_SCAN, 256, 0, stream>>>(deg, roff, bsum);
  scan_top <<<1, 256, 0, stream>>>(bsum);
  scan_add <<<NBLK_SCAN, 256, 0, stream>>>(roff, bsum);
  scatter_k<<<(N_EDGES + 255) / 256, 256, 0, stream>>>(ei, roff, cursor, ssrc);

  // ---- weight splits (AFTER scatter: alias dead deg/cursor) ----
  conv_w<<<(IN_CH * HC + OUT_CH * HC + 255) / 256, 256, 0, stream>>>(
      W1, W2, W1hT, W1lT, W2hT, W2lT);
  conv_wa<<<(32 * IN_CH + 255) / 256, 256, 0, stream>>>(
      W1, a_src1, a_dst1, W1hT, W1lT);

  // ---- layer 1 (es/ed fused into gemm1) ----
  gemm1_mfma<<<(N_NODES + 63) / 64, 256, 0, stream>>>(x, W1hT, W1lT, h1b, es1, ed1);
  agg1 <<<N_NODES / 8, 256, 0, stream>>>(roff, ssrc, es1, ed1, h1b, b1, acth, actl);

  // ---- layer 2 (edot2 fused into gemm2) ----
  hipMemsetAsync(pooled, 0, (size_t)N_GRAPHS * OUT_CH * 4, stream);
  gemm2_mfma<<<(N_NODES + 63) / 64, 256, 0, stream>>>(acth, actl, W2hT, W2lT,
                                                      a_src2, a_dst2, h2, es2, ed2);
  agg2 <<<N_NODES / 8, 256, 0, stream>>>(roff, ssrc, es2, ed2, h2, b2, batch, pooled);
  final_k<<<(N_GRAPHS * OUT_CH + 255) / 256, 256, 0, stream>>>(pooled, fc_w, fc_b, out);
}

// Round 22
// 350.147 us; speedup vs baseline: 1.7655x; 1.0169x over previous
//
#include <hip/hip_runtime.h>

#define N_NODES 50000
#define N_EDGES 800000
#define IN_CH   128
#define OUT_CH  32
#define HEADS   10
#define HC      320           // HEADS*OUT_CH
#define N_GRAPHS 512
#define NEG_SLOPE 0.2f
#define NBLK_SCAN 196         // ceil(50000/256)

typedef __attribute__((ext_vector_type(8))) short bf16x8;   // 8 bf16 in 4 VGPRs
typedef __attribute__((ext_vector_type(4))) float f32x4;
typedef __attribute__((ext_vector_type(4))) unsigned short usx4;  // native 8B vec

__device__ __forceinline__ unsigned fmap(float f) {
  unsigned u = __float_as_uint(f);
  return (u & 0x80000000u) ? ~u : (u | 0x80000000u);
}
__device__ __forceinline__ float funmap(unsigned u) {
  u = (u & 0x80000000u) ? (u ^ 0x80000000u) : ~u;
  return __uint_as_float(u);
}
__device__ __forceinline__ float leaky(float a) {
  return a > 0.f ? a : NEG_SLOPE * a;
}
__device__ __forceinline__ unsigned short f2bf(float f) {
  unsigned u = __float_as_uint(f);
  return (unsigned short)((u + 0x7FFFu + ((u >> 16) & 1u)) >> 16);
}
__device__ __forceinline__ float bf2f(unsigned short b) {
  return __uint_as_float(((unsigned)b) << 16);
}
__device__ __forceinline__ float bflo(unsigned u) { return __uint_as_float(u << 16); }
__device__ __forceinline__ float bfhi(unsigned u) { return __uint_as_float(u & 0xFFFF0000u); }
__device__ __forceinline__ void store_split(unsigned short* __restrict__ ph,
                                            unsigned short* __restrict__ pl,
                                            size_t idx, float v) {
  unsigned short h = f2bf(v);
  ph[idx] = h;
  pl[idx] = f2bf(v - bf2f(h));
}
__device__ __forceinline__ float elu(float v) {
  return v > 0.f ? v : expm1f(v);
}

// ============================ CSR construction =============================
__global__ __launch_bounds__(256) void hist_k(const int* __restrict__ ei,
                                              int* __restrict__ deg) {
  int e = blockIdx.x * 256 + threadIdx.x;
  if (e < N_EDGES) atomicAdd(&deg[ei[N_EDGES + e]], 1);
}

__global__ __launch_bounds__(256) void scan_blk(const int* __restrict__ deg,
                                                int* __restrict__ roff,
                                                int* __restrict__ bsum) {
  __shared__ int s[256];
  int i = blockIdx.x * 256 + threadIdx.x;
  int v = (i < N_NODES) ? deg[i] : 0;
  s[threadIdx.x] = v;
  __syncthreads();
  #pragma unroll
  for (int o = 1; o < 256; o <<= 1) {
    int t = (threadIdx.x >= o) ? s[threadIdx.x - o] : 0;
    __syncthreads();
    s[threadIdx.x] += t;
    __syncthreads();
  }
  if (i < N_NODES) roff[i] = s[threadIdx.x] - v;   // exclusive
  if (threadIdx.x == 255) bsum[blockIdx.x] = s[255];
}

__global__ __launch_bounds__(256) void scan_top(int* __restrict__ bsum) {
  __shared__ int s[256];
  int i = threadIdx.x;
  int v = (i < NBLK_SCAN) ? bsum[i] : 0;
  s[i] = v;
  __syncthreads();
  #pragma unroll
  for (int o = 1; o < 256; o <<= 1) {
    int t = (i >= o) ? s[i - o] : 0;
    __syncthreads();
    s[i] += t;
    __syncthreads();
  }
  if (i < NBLK_SCAN) bsum[i] = s[i] - v;           // exclusive
}

__global__ __launch_bounds__(256) void scan_add(int* __restrict__ roff,
                                                const int* __restrict__ bsum) {
  int i = blockIdx.x * 256 + threadIdx.x;
  if (i < N_NODES) roff[i] += bsum[blockIdx.x];
  if (i == 0) roff[N_NODES] = N_EDGES;
}

__global__ __launch_bounds__(256) void scatter_k(const int* __restrict__ ei,
                                                 const int* __restrict__ roff,
                                                 int* __restrict__ cursor,
                                                 int* __restrict__ ssrc) {
  int e = blockIdx.x * 256 + threadIdx.x;
  if (e >= N_EDGES) return;
  int dst = ei[N_EDGES + e];
  int pos = roff[dst] + atomicAdd(&cursor[dst], 1);
  ssrc[pos] = ei[e];
}

// ======== weight splits: W1T[352][128] hi/lo (cols 320+ = fused edot) ======
__global__ __launch_bounds__(256) void conv_w(const float* __restrict__ W1,
                                              const float* __restrict__ W2,
                                              unsigned short* __restrict__ W1hT,
                                              unsigned short* __restrict__ W1lT,
                                              unsigned short* __restrict__ W2hT,
                                              unsigned short* __restrict__ W2lT) {
  int i = blockIdx.x * 256 + threadIdx.x;
  if (i < IN_CH * HC) {                 // i = n*128 + k
    int n = i >> 7, k = i & 127;
    float v = W1[(size_t)k * HC + n];
    unsigned short h = f2bf(v);
    W1hT[i] = h; W1lT[i] = f2bf(v - bf2f(h));
  } else {
    int j = i - IN_CH * HC;
    if (j < OUT_CH * HC) {              // j = c*320 + k
      int c = j / HC, k = j - c * HC;
      float v = W2[(size_t)k * OUT_CH + c];
      unsigned short h = f2bf(v);
      W2hT[j] = h; W2lT[j] = f2bf(v - bf2f(h));
    }
  }
}

__global__ __launch_bounds__(256) void conv_wa(const float* __restrict__ W1,
                                               const float* __restrict__ a_src1,
                                               const float* __restrict__ a_dst1,
                                               unsigned short* __restrict__ W1hT,
                                               unsigned short* __restrict__ W1lT) {
  int i = blockIdx.x * 256 + threadIdx.x;   // i = j*128 + k, j=0..31
  if (i >= 32 * IN_CH) return;
  int j = i >> 7, k = i & 127;
  float v = 0.f;
  if (j < 20) {
    int head = (j < 10) ? j : (j - 10);
    const float* a = (j < 10) ? (a_src1 + head * OUT_CH) : (a_dst1 + head * OUT_CH);
    const float* wrow = W1 + (size_t)k * HC + head * OUT_CH;
    #pragma unroll
    for (int c = 0; c < OUT_CH; c++) v += wrow[c] * a[c];
  }
  unsigned short h = f2bf(v);
  W1hT[(size_t)(HC + j) * IN_CH + k] = h;
  W1lT[(size_t)(HC + j) * IN_CH + k] = f2bf(v - bf2f(h));
}

// == GEMM1 (fused X-split + fused edot1): h1b = X@W1 (bf16); es/ed = X@W1a ==
__global__ __launch_bounds__(256) void gemm1_mfma(const float* __restrict__ X,
                                                  const unsigned short* __restrict__ WhT,
                                                  const unsigned short* __restrict__ WlT,
                                                  unsigned short* __restrict__ Hb,
                                                  float* __restrict__ es,
                                                  float* __restrict__ ed) {
  const int wave = threadIdx.x >> 6;
  const int lane = threadIdx.x & 63;
  const int row0 = blockIdx.x * 64 + wave * 16;
  const int r = lane & 15;
  const int kg = lane >> 4;                          // 0..3
  int arow = row0 + r; if (arow >= N_NODES) arow = N_NODES - 1;
  const float* xrow = X + (size_t)arow * IN_CH + kg * 8;
  const unsigned short* wb = WhT + (size_t)r * IN_CH + kg * 8;   // col-tile 0
  const unsigned short* lb = WlT + (size_t)r * IN_CH + kg * 8;
  f32x4 acc[22];
  #pragma unroll
  for (int c = 0; c < 22; c++) acc[c] = f32x4{0.f, 0.f, 0.f, 0.f};
  #pragma unroll
  for (int k0 = 0; k0 < IN_CH; k0 += 32) {
    float4 u = *reinterpret_cast<const float4*>(xrow + k0);
    float4 w = *reinterpret_cast<const float4*>(xrow + k0 + 4);
    float uv0 = u.x, uv1 = u.y, uv2 = u.z, uv3 = u.w;
    float uv4 = w.x, uv5 = w.y, uv6 = w.z, uv7 = w.w;
    bf16x8 ah, al;
    unsigned short hh;
    hh = f2bf(uv0); ah[0] = (short)hh; al[0] = (short)f2bf(uv0 - bf2f(hh));
    hh = f2bf(uv1); ah[1] = (short)hh; al[1] = (short)f2bf(uv1 - bf2f(hh));
    hh = f2bf(uv2); ah[2] = (short)hh; al[2] = (short)f2bf(uv2 - bf2f(hh));
    hh = f2bf(uv3); ah[3] = (short)hh; al[3] = (short)f2bf(uv3 - bf2f(hh));
    hh = f2bf(uv4); ah[4] = (short)hh; al[4] = (short)f2bf(uv4 - bf2f(hh));
    hh = f2bf(uv5); ah[5] = (short)hh; al[5] = (short)f2bf(uv5 - bf2f(hh));
    hh = f2bf(uv6); ah[6] = (short)hh; al[6] = (short)f2bf(uv6 - bf2f(hh));
    hh = f2bf(uv7); ah[7] = (short)hh; al[7] = (short)f2bf(uv7 - bf2f(hh));
    #pragma unroll
    for (int c = 0; c < 22; c++) {
      bf16x8 bh = *reinterpret_cast<const bf16x8*>(wb + (size_t)c * 16 * IN_CH + k0);
      bf16x8 bl = *reinterpret_cast<const bf16x8*>(lb + (size_t)c * 16 * IN_CH + k0);
      acc[c] = __builtin_amdgcn_mfma_f32_16x16x32_bf16(ah, bh, acc[c], 0, 0, 0);
      acc[c] = __builtin_amdgcn_mfma_f32_16x16x32_bf16(ah, bl, acc[c], 0, 0, 0);
      acc[c] = __builtin_amdgcn_mfma_f32_16x16x32_bf16(al, bh, acc[c], 0, 0, 0);
    }
  }
  const int crow0 = row0 + kg * 4;
  #pragma unroll
  for (int c = 0; c < 20; c++) {
    const int ccol = c * 16 + r;
    #pragma unroll
    for (int t = 0; t < 4; t++) {
      int rr = crow0 + t;
      if (rr < N_NODES) Hb[(size_t)rr * HC + ccol] = f2bf(acc[c][t]);
    }
  }
  #pragma unroll
  for (int t = 0; t < 4; t++) {
    int rr = crow0 + t;
    if (rr < N_NODES) {
      float v20 = acc[20][t];
      if (r < 10) es[rr * 10 + r] = v20;
      else        ed[rr * 10 + (r - 10)] = v20;
      if (r < 4)  ed[rr * 10 + 6 + r] = acc[21][t];
    }
  }
}

// === GEMM2 + fused edot2: h2[N,32](f32) = act @ W2 ; es/ed = h2 . a_{s,d} ==
__global__ __launch_bounds__(256) void gemm2_mfma(const unsigned short* __restrict__ Ah,
                                                  const unsigned short* __restrict__ Al,
                                                  const unsigned short* __restrict__ WhT,
                                                  const unsigned short* __restrict__ WlT,
                                                  const float* __restrict__ a_src2,
                                                  const float* __restrict__ a_dst2,
                                                  float* __restrict__ H,
                                                  float* __restrict__ es,
                                                  float* __restrict__ ed) {
  const int wave = threadIdx.x >> 6;
  const int lane = threadIdx.x & 63;
  const int row0 = blockIdx.x * 64 + wave * 16;
  const int r = lane & 15;
  const int kg = lane >> 4;
  int arow = row0 + r; if (arow >= N_NODES) arow = N_NODES - 1;
  const unsigned short* ah_p = Ah + (size_t)arow * HC + kg * 8;
  const unsigned short* al_p = Al + (size_t)arow * HC + kg * 8;
  const unsigned short* wb = WhT + (size_t)r * HC + kg * 8;
  const unsigned short* lb = WlT + (size_t)r * HC + kg * 8;
  f32x4 acc[2];
  acc[0] = f32x4{0.f, 0.f, 0.f, 0.f};
  acc[1] = f32x4{0.f, 0.f, 0.f, 0.f};
  #pragma unroll
  for (int k0 = 0; k0 < HC; k0 += 32) {
    bf16x8 ah = *reinterpret_cast<const bf16x8*>(ah_p + k0);
    bf16x8 al = *reinterpret_cast<const bf16x8*>(al_p + k0);
    #pragma unroll
    for (int c = 0; c < 2; c++) {
      bf16x8 bh = *reinterpret_cast<const bf16x8*>(wb + (size_t)c * 16 * HC + k0);
      bf16x8 bl = *reinterpret_cast<const bf16x8*>(lb + (size_t)c * 16 * HC + k0);
      acc[c] = __builtin_amdgcn_mfma_f32_16x16x32_bf16(ah, bh, acc[c], 0, 0, 0);
      acc[c] = __builtin_amdgcn_mfma_f32_16x16x32_bf16(ah, bl, acc[c], 0, 0, 0);
      acc[c] = __builtin_amdgcn_mfma_f32_16x16x32_bf16(al, bh, acc[c], 0, 0, 0);
    }
  }
  const int crow0 = row0 + kg * 4;
  #pragma unroll
  for (int c = 0; c < 2; c++) {
    const int ccol = c * 16 + r;
    #pragma unroll
    for (int t = 0; t < 4; t++) {
      int rr = crow0 + t;
      if (rr < N_NODES) H[(size_t)rr * OUT_CH + ccol] = acc[c][t];
    }
  }
  const float as0 = a_src2[r], as1 = a_src2[16 + r];
  const float ad0 = a_dst2[r], ad1 = a_dst2[16 + r];
  float pe[4], pd[4];
  #pragma unroll
  for (int t = 0; t < 4; t++) {
    pe[t] = acc[0][t] * as0 + acc[1][t] * as1;
    pd[t] = acc[0][t] * ad0 + acc[1][t] * ad1;
  }
  #pragma unroll
  for (int o = 1; o < 16; o <<= 1) {
    #pragma unroll
    for (int t = 0; t < 4; t++) {
      pe[t] += __shfl_xor(pe[t], o);
      pd[t] += __shfl_xor(pd[t], o);
    }
  }
  if (r == 0) {
    #pragma unroll
    for (int t = 0; t < 4; t++) {
      int rr = crow0 + t;
      if (rr < N_NODES) { es[rr] = pe[t]; ed[rr] = pd[t]; }
    }
  }
}

// ------ layer-1 aggregation: one wave per dst node (R18 structure) ---------
// Phase 1: lane e owns edge e; ex[10] -> LDS (+ src byte-offset).
// Phase 2: 2 edges/iter; in-loop denominators; plain cached stores.
__global__ __launch_bounds__(256) void agg1(const int* __restrict__ roff,
                                            const int* __restrict__ ssrc,
                                            const float* __restrict__ es,
                                            const float* __restrict__ ed,
                                            const unsigned short* __restrict__ h1b,
                                            const float* __restrict__ b1,
                                            unsigned short* __restrict__ acth,
                                            unsigned short* __restrict__ actl) {
  __shared__ float lds[4][64][11];   // [wave][edge][0..9]=ex, [10]=byteoff bits
  const int n = (blockIdx.x * 256 + threadIdx.x) >> 6;
  if (n >= N_NODES) return;
  const int wslot = threadIdx.x >> 6;
  const int lane = threadIdx.x & 63;
  const int beg = roff[n];
  const int deg = roff[n + 1] - beg;

  if (deg == 0) {
    #pragma unroll
    for (int q = 0; q < 5; q++) {
      float v = elu(b1[lane + 64 * q]);
      store_split(acth, actl, (size_t)n * HC + lane + 64 * q, v);
    }
    return;
  }

  if (deg <= 64) {
    // ---- phase 1 ----
    const int active = (lane < deg);
    const int src = ssrc[beg + (active ? lane : 0)];
    #pragma unroll
    for (int p = 0; p < 5; p++) {
      float2 edp = *reinterpret_cast<const float2*>(ed + n * 10 + 2 * p);
      float2 esp = *reinterpret_cast<const float2*>(es + src * 10 + 2 * p);
      lds[wslot][lane][2 * p]     = active ? expf(leaky(esp.x + edp.x)) : 0.f;
      lds[wslot][lane][2 * p + 1] = active ? expf(leaky(esp.y + edp.y)) : 0.f;
    }
    lds[wslot][lane][10] = __int_as_float(src * (HC * 2));   // byte offset

    // ---- phase 2: 2 edges/iter, uint4 main + uint tail, in-loop denoms ----
    const int half = lane >> 5;
    const int lc = lane & 31;
    const int hm = lc >> 2;            // head of main cols 8lc..8lc+7
    const int ht = 8 + (lc >> 4);      // head of tail cols 256+2lc..+1
    float accm[8] = {};
    float acct0 = 0.f, acct1 = 0.f, dm = 0.f, dt = 0.f;
    const int dege = (deg + 1) & ~1;   // edges >= deg have ex=0, valid off
    const char* basem = reinterpret_cast<const char*>(h1b + 8 * lc);
    const char* baset = reinterpret_cast<const char*>(h1b + 256 + 2 * lc);
    for (int j = 0; j < dege; j += 2) {
      const int e = j + half;
      int off = __float_as_int(lds[wslot][e][10]);
      float cm = lds[wslot][e][hm];
      float ct = lds[wslot][e][ht];
      uint4 v = *reinterpret_cast<const uint4*>(basem + off);
      unsigned t = *reinterpret_cast<const unsigned*>(baset + off);
      unsigned w0 = v.x, w1 = v.y, w2 = v.z, w3 = v.w;
      accm[0] = fmaf(bflo(w0), cm, accm[0]);
      accm[1] = fmaf(bfhi(w0), cm, accm[1]);
      accm[2] = fmaf(bflo(w1), cm, accm[2]);
      accm[3] = fmaf(bfhi(w1), cm, accm[3]);
      accm[4] = fmaf(bflo(w2), cm, accm[4]);
      accm[5] = fmaf(bfhi(w2), cm, accm[5]);
      accm[6] = fmaf(bflo(w3), cm, accm[6]);
      accm[7] = fmaf(bfhi(w3), cm, accm[7]);
      acct0 = fmaf(bflo(t), ct, acct0);
      acct1 = fmaf(bfhi(t), ct, acct1);
      dm += cm;
      dt += ct;
    }
    // merge halves
    #pragma unroll
    for (int k = 0; k < 8; k++) accm[k] += __shfl_xor(accm[k], 32);
    acct0 += __shfl_xor(acct0, 32);
    acct1 += __shfl_xor(acct1, 32);
    dm += __shfl_xor(dm, 32);
    dt += __shfl_xor(dt, 32);

    if (lane < 32) {
      const float invm = 1.f / (dm + 1e-16f);
      const size_t base = (size_t)n * HC;
      usx4 sh0, sl0, sh1, sl1;
      float vv;
      unsigned short hh;
      vv = elu(accm[0] * invm + b1[8 * lc + 0]); hh = f2bf(vv); sh0[0] = hh; sl0[0] = f2bf(vv - bf2f(hh));
      vv = elu(accm[1] * invm + b1[8 * lc + 1]); hh = f2bf(vv); sh0[1] = hh; sl0[1] = f2bf(vv - bf2f(hh));
      vv = elu(accm[2] * invm + b1[8 * lc + 2]); hh = f2bf(vv); sh0[2] = hh; sl0[2] = f2bf(vv - bf2f(hh));
      vv = elu(accm[3] * invm + b1[8 * lc + 3]); hh = f2bf(vv); sh0[3] = hh; sl0[3] = f2bf(vv - bf2f(hh));
      vv = elu(accm[4] * invm + b1[8 * lc + 4]); hh = f2bf(vv); sh1[0] = hh; sl1[0] = f2bf(vv - bf2f(hh));
      vv = elu(accm[5] * invm + b1[8 * lc + 5]); hh = f2bf(vv); sh1[1] = hh; sl1[1] = f2bf(vv - bf2f(hh));
      vv = elu(accm[6] * invm + b1[8 * lc + 6]); hh = f2bf(vv); sh1[2] = hh; sl1[2] = f2bf(vv - bf2f(hh));
      vv = elu(accm[7] * invm + b1[8 * lc + 7]); hh = f2bf(vv); sh1[3] = hh; sl1[3] = f2bf(vv - bf2f(hh));
      *reinterpret_cast<usx4*>(acth + base + 8 * lc) = sh0;
      *reinterpret_cast<usx4*>(acth + base + 8 * lc + 4) = sh1;
      *reinterpret_cast<usx4*>(actl + base + 8 * lc) = sl0;
      *reinterpret_cast<usx4*>(actl + base + 8 * lc + 4) = sl1;
      const float invt = 1.f / (dt + 1e-16f);
      unsigned tph, tpl;
      unsigned short h0, h1v, l0, l1v;
      vv = elu(acct0 * invt + b1[256 + 2 * lc + 0]); h0 = f2bf(vv); l0 = f2bf(vv - bf2f(h0));
      vv = elu(acct1 * invt + b1[256 + 2 * lc + 1]); h1v = f2bf(vv); l1v = f2bf(vv - bf2f(h1v));
      tph = (unsigned)h0 | ((unsigned)h1v << 16);
      tpl = (unsigned)l0 | ((unsigned)l1v << 16);
      *reinterpret_cast<unsigned*>(acth + base + 256 + 2 * lc) = tph;
      *reinterpret_cast<unsigned*>(actl + base + 256 + 2 * lc) = tpl;
    }
  } else {
    // ---- slow fallback (deg > 64): per-lane redundant 2-pass ----
    const int hb = lane >> 5;
    float acc[5] = {};
    float edv[5], m2[5];
    #pragma unroll
    for (int q = 0; q < 5; q++) { edv[q] = ed[n * 10 + 2 * q + hb]; m2[q] = -1e30f; }
    for (int j = beg; j < beg + deg; j++) {
      int src = ssrc[j];
      #pragma unroll
      for (int q = 0; q < 5; q++)
        m2[q] = fmaxf(m2[q], leaky(es[src * 10 + 2 * q + hb] + edv[q]));
    }
    float d2[5] = {};
    for (int j = beg; j < beg + deg; j++) {
      int src = ssrc[j];
      const unsigned short* hrow = h1b + (size_t)src * HC + lane;
      #pragma unroll
      for (int q = 0; q < 5; q++) {
        float ex = expf(leaky(es[src * 10 + 2 * q + hb] + edv[q]) - m2[q]);
        acc[q] = fmaf(bf2f(hrow[64 * q]), ex, acc[q]);
        d2[q] += ex;
      }
    }
    #pragma unroll
    for (int q = 0; q < 5; q++) {
      float v = elu(acc[q] / (d2[q] + 1e-16f) + b1[lane + 64 * q]);
      store_split(acth, actl, (size_t)n * HC + lane + 64 * q, v);
    }
  }
}

// ------ layer-2 aggregation: one wave per node, in-loop denom, fused pool --
__global__ __launch_bounds__(256) void agg2(const int* __restrict__ roff,
                                            const int* __restrict__ ssrc,
                                            const float* __restrict__ es,
                                            const float* __restrict__ ed,
                                            const float* __restrict__ h2,
                                            const float* __restrict__ b2,
                                            const int* __restrict__ batch,
                                            unsigned* __restrict__ pooled) {
  __shared__ float lds[4][64][2];    // [wave][edge][0]=ex, [1]=byteoff bits
  const int n = (blockIdx.x * 256 + threadIdx.x) >> 6;
  if (n >= N_NODES) return;
  const int wslot = threadIdx.x >> 6;
  const int lane = threadIdx.x & 63;
  const int c = lane & 31;
  const int hb = lane >> 5;
  const int beg = roff[n];
  const int deg = roff[n + 1] - beg;
  const int g = batch[n];

  if (deg == 0) {
    if (lane < 32) {
      float v = elu(b2[c]);
      atomicMax(&pooled[g * OUT_CH + c], fmap(v));
    }
    return;
  }

  float acc = 0.f, dacc = 0.f, dtot;

  if (deg <= 64) {
    const int active = (lane < deg);
    const int src = ssrc[beg + (active ? lane : 0)];
    const float edv = ed[n];
    float ex = active ? expf(leaky(es[src] + edv)) : 0.f;
    lds[wslot][lane][0] = ex;
    lds[wslot][lane][1] = __int_as_float(src * (OUT_CH * 4));  // byte offset
    const char* baseh = reinterpret_cast<const char*>(h2 + c);
    int j = hb;
    for (; j + 6 < deg; j += 8) {
      int o0 = __float_as_int(lds[wslot][j + 0][1]);
      int o1 = __float_as_int(lds[wslot][j + 2][1]);
      int o2 = __float_as_int(lds[wslot][j + 4][1]);
      int o3 = __float_as_int(lds[wslot][j + 6][1]);
      float c0 = lds[wslot][j + 0][0];
      float c1 = lds[wslot][j + 2][0];
      float c2 = lds[wslot][j + 4][0];
      float c3 = lds[wslot][j + 6][0];
      float v0 = *reinterpret_cast<const float*>(baseh + o0);
      float v1 = *reinterpret_cast<const float*>(baseh + o1);
      float v2 = *reinterpret_cast<const float*>(baseh + o2);
      float v3 = *reinterpret_cast<const float*>(baseh + o3);
      acc = fmaf(v0, c0, acc);
      acc = fmaf(v1, c1, acc);
      acc = fmaf(v2, c2, acc);
      acc = fmaf(v3, c3, acc);
      dacc += c0 + c1 + c2 + c3;
    }
    for (; j < deg; j += 2) {
      int oj = __float_as_int(lds[wslot][j][1]);
      float cj = lds[wslot][j][0];
      acc = fmaf(*reinterpret_cast<const float*>(baseh + oj), cj, acc);
      dacc += cj;
    }
    acc += __shfl_xor(acc, 32);
    dacc += __shfl_xor(dacc, 32);
    dtot = dacc;
  } else {
    const float edv = ed[n];
    float m = -1e30f;
    for (int j = beg; j < beg + deg; j++)
      m = fmaxf(m, leaky(es[ssrc[j]] + edv));
    float d = 0.f;
    for (int j = beg + hb; j < beg + deg; j += 2) {
      int src = ssrc[j];
      float ex = expf(leaky(es[src] + edv) - m);
      acc = fmaf(h2[(size_t)src * OUT_CH + c], ex, acc);
      d += ex;
    }
    acc += __shfl_xor(acc, 32);
    d += __shfl_xor(d, 32);
    dtot = d;
  }

  if (lane < 32) {
    float v = elu(acc / (dtot + 1e-16f) + b2[c]);
    atomicMax(&pooled[g * OUT_CH + c], fmap(v));
  }
}

// -------- final: out[g,c] = relu(pooled[g,:] @ fc_w[:,c] + fc_b[c]) --------
__global__ __launch_bounds__(256) void final_k(const unsigned* __restrict__ pooled,
                                               const float* __restrict__ fc_w,
                                               const float* __restrict__ fc_b,
                                               float* __restrict__ out) {
  int idx = blockIdx.x * 256 + threadIdx.x;
  if (idx >= N_GRAPHS * OUT_CH) return;
  int g = idx >> 5, c = idx & 31;
  float s = fc_b[c];
  #pragma unroll
  for (int k = 0; k < OUT_CH; k++) {
    unsigned u = pooled[g * OUT_CH + k];
    float p = (u == 0u) ? 0.f : funmap(u);
    s += p * fc_w[k * OUT_CH + c];
  }
  out[idx] = s > 0.f ? s : 0.f;
}

extern "C" void kernel_launch(void* const* d_in, const int* in_sizes, int n_in,
                              void* d_out, int out_size, void* d_ws, size_t ws_size,
                              hipStream_t stream) {
  const float* x      = (const float*)d_in[0];
  const int*   ei     = (const int*)d_in[1];
  const int*   batch  = (const int*)d_in[2];
  const float* W1     = (const float*)d_in[4];
  const float* a_src1 = (const float*)d_in[5];
  const float* a_dst1 = (const float*)d_in[6];
  const float* b1     = (const float*)d_in[7];
  const float* W2     = (const float*)d_in[8];
  const float* a_src2 = (const float*)d_in[9];
  const float* a_dst2 = (const float*)d_in[10];
  const float* b2     = (const float*)d_in[11];
  const float* fc_w   = (const float*)d_in[12];
  const float* fc_b   = (const float*)d_in[13];
  float* out = (float*)d_out;

  // ---- workspace layout (<= 136 MB, phase-aliased) ----
  // A [0,64M): h1b bf16 32MB; h2 f32 aliases head after agg1
  // B [64M,128M): act_h|act_l (64M)
  // S [128M,136M): CSR + es/ed + pooled; W-splits alias dead deg/cursor
  char* ws = (char*)d_ws;
  unsigned short* h1b = (unsigned short*)(ws);              // 32 MB
  float* h2   = (float*)(ws);                               // after agg1
  unsigned short* acth = (unsigned short*)(ws + 64000000);  // 32 MB
  unsigned short* actl = (unsigned short*)(ws + 96000000);  // 32 MB
  char*  S    = ws + 128000000;
  int*   ssrc   = (int*)(S);                  // 3.2 MB
  int*   roff   = (int*)(S + 3200000);        // 200,004 B
  int*   deg    = (int*)(S + 3400064);        // 200,000 B (dead after scan)
  int*   cursor = (int*)(S + 3600064);        // 200,000 B (dead after scatter)
  unsigned short* W1hT = (unsigned short*)(S + 3400064);                // 90,112 B
  unsigned short* W1lT = (unsigned short*)(S + 3400064 + 90112);        // 90,112 B
  unsigned short* W2hT = (unsigned short*)(S + 3400064 + 180224);       // 20,480 B
  unsigned short* W2lT = (unsigned short*)(S + 3400064 + 200704);       // 20,480 B
  float* es1    = (float*)(S + 3800064);      // 2 MB
  float* ed1    = (float*)(S + 5800064);      // 2 MB
  int*   bsum   = (int*)(S + 7800064);        // 784 B
  unsigned* pooled = (unsigned*)(S + 7801600);// 64 KB
  float* es2 = es1; float* ed2 = ed1;         // dead after agg1

  // ---- CSR build ----
  hipMemsetAsync(deg, 0, (size_t)N_NODES * 4, stream);
  hipMemsetAsync(cursor, 0, (size_t)N_NODES * 4, stream);
  hist_k   <<<(N_EDGES + 255) / 256, 256, 0, stream>>>(ei, deg);
  scan_blk <<<NBLK_SCAN, 256, 0, stream>>>(deg, roff, bsum);
  scan_top <<<1, 256, 0, stream>>>(bsum);
  scan_add <<<NBLK_SCAN, 256, 0, stream>>>(roff, bsum);
  scatter_k<<<(N_EDGES + 255) / 256, 256, 0, stream>>>(ei, roff, cursor, ssrc);

  // ---- weight splits (AFTER scatter: alias dead deg/cursor) ----
  conv_w<<<(IN_CH * HC + OUT_CH * HC + 255) / 256, 256, 0, stream>>>(
      W1, W2, W1hT, W1lT, W2hT, W2lT);
  conv_wa<<<(32 * IN_CH + 255) / 256, 256, 0, stream>>>(
      W1, a_src1, a_dst1, W1hT, W1lT);

  // ---- layer 1 (es/ed fused into gemm1) ----
  gemm1_mfma<<<(N_NODES + 63) / 64, 256, 0, stream>>>(x, W1hT, W1lT, h1b, es1, ed1);
  agg1 <<<(N_NODES * 64 + 255) / 256, 256, 0, stream>>>(roff, ssrc, es1, ed1, h1b, b1,
                                                        acth, actl);

  // ---- layer 2 (edot2 fused into gemm2) ----
  hipMemsetAsync(pooled, 0, (size_t)N_GRAPHS * OUT_CH * 4, stream);
  gemm2_mfma<<<(N_NODES + 63) / 64, 256, 0, stream>>>(acth, actl, W2hT, W2lT,
                                                      a_src2, a_dst2, h2, es2, ed2);
  agg2 <<<(N_NODES * 64 + 255) / 256, 256, 0, stream>>>(roff, ssrc, es2, ed2, h2, b2,
                                                        batch, pooled);
  final_k<<<(N_GRAPHS * OUT_CH + 255) / 256, 256, 0, stream>>>(pooled, fc_w, fc_b, out);
}